// Round 1
// baseline (486.738 us; speedup 1.0000x reference)
//
#include <hip/hip_runtime.h>

// RGCN 2-layer: N=1e6 nodes, E=16e6 edges, 3 relations, C: 3 -> 2 -> 2.
//
// R9: scatter was 135us at 20% HBM / 32% VALU / 77% occ -> structurally
// serialized. Two suspects fixed: (1) reserve-phase cursor atomics: 955K
// device atomics on 61 cache lines (16 cursors/line) convoy at the coherence
// point -> cursor now padded to 1 per 64B line (BCAP 18432->18368 to keep ws
// need constant). (2) VGPR=12: scalar unpipelined loads -> int4-vectorized
// dst/src/rel streams, dst held in regs across the scan (no pass-B re-read).
// Aggs: 8 consecutive entries per thread via 2x uint4 + next-group prefetch
// pipeline (buf stream hides under qx/qh gathers).
// Carried: bucket-sorted edge buffer + LDS packed-u64 accumulation + 4B/node
// quantized gather tables qx/qh (L2-resident).
// Entry = src:20|rel:2|local:10. LDS cell [cnt:8|s1:28|s0:28], scale 4096,
// +2^19/edge bias -> exact integer associativity. Threshold 6.3e-2, R7 absmax 0.0156.

typedef unsigned long long u64;
typedef unsigned u32;

constexpr int NN = 1000000;
constexpr int NE = 16000000;
constexpr int NR = 3;

constexpr int BSH   = 10;                   // 1024 nodes per bucket
constexpr int NB    = (NN + 1023) >> 10;    // 977 buckets
constexpr int BCAP  = 18368;                // per-bucket entry capacity (~+15 sigma)
constexpr int CSTR  = 16;                   // cursor stride in u32 (one per 64B line)
constexpr int EPB   = 16384;                // edges per scatter block
constexpr int NBLKB = (NE + EPB - 1) / EPB; // 977 scatter blocks

constexpr u64 M28 = (1ULL << 28) - 1;

__device__ __forceinline__ u64 pack_msg(float m0, float m1) {
    int a0 = __float2int_rn(fmaf(m0, 4096.0f, 524288.0f));  // + 2^19 bias
    int a1 = __float2int_rn(fmaf(m1, 4096.0f, 524288.0f));
    return (u64)(u32)a0 | ((u64)(u32)a1 << 28) | (1ULL << 56);
}

__device__ __forceinline__ u32 enc_x(float x0, float x1, float x2) {
    int q0 = __float2int_rn(fminf(fmaxf(x0 * 64.0f, -511.0f), 511.0f));
    int q1 = __float2int_rn(fminf(fmaxf(x1 * 128.0f, -1023.0f), 1023.0f));
    int q2 = __float2int_rn(fminf(fmaxf(x2 * 128.0f, -1023.0f), 1023.0f));
    return ((u32)q0 & 0x3FFu) | (((u32)q1 & 0x7FFu) << 10) | (((u32)q2 & 0x7FFu) << 21);
}

__device__ __forceinline__ void dec_x(u32 e, float& x0, float& x1, float& x2) {
    x0 = (float)((int)(e << 22) >> 22) * (1.0f / 64.0f);
    x1 = (float)((int)(e << 11) >> 21) * (1.0f / 128.0f);
    x2 = (float)((int)e >> 21)         * (1.0f / 128.0f);
}

__device__ __forceinline__ u32 enc_h(float h0, float h1) {
    int q0 = __float2int_rn(fminf(h0 * 1024.0f, 32767.0f));  // h >= 0 (relu)
    int q1 = __float2int_rn(fminf(h1 * 1024.0f, 32767.0f));
    return ((u32)q0 & 0xFFFFu) | ((u32)q1 << 16);
}

__device__ __forceinline__ void dec_h(u32 e, float& h0, float& h1) {
    h0 = (float)((int)(e << 16) >> 16) * (1.0f / 1024.0f);
    h1 = (float)((int)e >> 16)         * (1.0f / 1024.0f);
}

// ---------------- fast path ----------------

__global__ __launch_bounds__(256) void prep_qx_kernel(
    const float* __restrict__ x, u32* __restrict__ qx)
{
    int n = blockIdx.x * 256 + threadIdx.x;
    if (n >= NN) return;
    qx[n] = enc_x(x[3 * n + 0], x[3 * n + 1], x[3 * n + 2]);
}

__global__ __launch_bounds__(1024, 8) void scatter_kernel(
    const int* __restrict__ src, const int* __restrict__ dst, const int* __restrict__ rel,
    u32* __restrict__ buf, u32* __restrict__ cursor)
{
    __shared__ u32 stage[EPB];     // 64 KiB: entries sorted by bucket
    __shared__ u32 hist[1024];
    __shared__ u32 wcur[1024];
    __shared__ u32 gbase[1024];
    __shared__ u32 wt[16];
    const int tid = threadIdx.x;
    const int wave = tid >> 6, lane = tid & 63;

    hist[tid] = 0;
    __syncthreads();

    const int base = blockIdx.x * EPB;
    const int nloc = min(EPB, NE - base);   // always a multiple of 4

    // pass A: vectorized dst loads; keep all 16 dsts in registers
    int4 d4[4];
#pragma unroll
    for (int c = 0; c < 4; ++c) {
        int idx = (c << 10) + tid;          // int4 index within block window
        if ((idx << 2) < nloc) {
            d4[c] = ((const int4*)(dst + base))[idx];
        } else {
            d4[c] = make_int4(-1, -1, -1, -1);
        }
    }
#pragma unroll
    for (int c = 0; c < 4; ++c) {
        if ((((c << 10) + tid) << 2) < nloc) {
            atomicAdd(&hist[((u32)d4[c].x) >> BSH], 1u);
            atomicAdd(&hist[((u32)d4[c].y) >> BSH], 1u);
            atomicAdd(&hist[((u32)d4[c].z) >> BSH], 1u);
            atomicAdd(&hist[((u32)d4[c].w) >> BSH], 1u);
        }
    }
    __syncthreads();

    // exclusive scan: one hist element per thread, wave shuffle + 16 wave totals
    {
        int h0 = hist[tid];
        int v0 = h0;
#pragma unroll
        for (int d = 1; d < 64; d <<= 1) {
            int t = __shfl_up(v0, d);
            if (lane >= d) v0 += t;
        }
        if (lane == 63) wt[wave] = (u32)v0;
        __syncthreads();
        u32 off = 0;
#pragma unroll
        for (int wv = 0; wv < 16; ++wv) off += (wv < wave) ? wt[wv] : 0u;
        wcur[tid] = off + (u32)(v0 - h0);
    }
    __syncthreads();

    // reserve global chunks (1 atomic per (block,bucket); cursor line-padded)
    if (tid < NB) {
        u32 c = hist[tid];
        gbase[tid] = c ? atomicAdd(&cursor[tid * CSTR], c) : 0u;
    }
    __syncthreads();

    // pass B: place entries into stage, bucket-sorted (dst from registers)
#pragma unroll 1
    for (int c = 0; c < 4; ++c) {
        int idx = (c << 10) + tid;
        if ((idx << 2) < nloc) {
            int4 s4 = ((const int4*)(src + base))[idx];
            int4 r4 = ((const int4*)(rel + base))[idx];
            {
                u32 d = (u32)d4[c].x, bk = d >> BSH;
                u32 sl = atomicAdd(&wcur[bk], 1u);
                stage[sl] = (u32)s4.x | ((u32)r4.x << 20) | ((d & 1023u) << 22);
            }
            {
                u32 d = (u32)d4[c].y, bk = d >> BSH;
                u32 sl = atomicAdd(&wcur[bk], 1u);
                stage[sl] = (u32)s4.y | ((u32)r4.y << 20) | ((d & 1023u) << 22);
            }
            {
                u32 d = (u32)d4[c].z, bk = d >> BSH;
                u32 sl = atomicAdd(&wcur[bk], 1u);
                stage[sl] = (u32)s4.z | ((u32)r4.z << 20) | ((d & 1023u) << 22);
            }
            {
                u32 d = (u32)d4[c].w, bk = d >> BSH;
                u32 sl = atomicAdd(&wcur[bk], 1u);
                stage[sl] = (u32)s4.w | ((u32)r4.w << 20) | ((d & 1023u) << 22);
            }
        }
    }
    __syncthreads();

    // pass C: burst-write each bucket's run (coalesced, contiguous lines)
    for (int b = wave; b < NB; b += 16) {
        u32 cnt = hist[b];
        if (!cnt) continue;
        u32 ls = wcur[b] - cnt;   // after pass B, wcur[b] == inclusive prefix
        u32 gb = gbase[b];
        u32* bb = buf + (size_t)b * BCAP;
        for (u32 j = lane; j < cnt; j += 64) {
            u32 slot = gb + j;
            if (slot < (u32)BCAP) bb[slot] = stage[ls + j];
        }
    }
}

__global__ __launch_bounds__(512, 8) void agg1_kernel(
    const u32* __restrict__ buf, const u32* __restrict__ cursor,
    const u32* __restrict__ qx, const float* __restrict__ x,
    const float* __restrict__ W1,
    const float* __restrict__ root1, const float* __restrict__ b1,
    u32* __restrict__ qh)
{
    __shared__ u64 acc[1024 * NR];   // 24 KiB
    __shared__ float w[NR * 3 * 2];
    const int tid = threadIdx.x;
    for (int i = tid; i < 1024 * NR; i += 512) acc[i] = 0;
    if (tid < NR * 3 * 2) w[tid] = W1[tid];
    __syncthreads();

    const int bk = blockIdx.x;
    const int n = min((int)cursor[bk * CSTR], BCAP);
    const u32* bb = buf + (size_t)bk * BCAP;
    const int n8 = n >> 3;           // groups of 8 consecutive entries

    // pipelined main loop: next group's entry loads issue before current
    // group's gathers/compute
    int g = tid;
    uint4 A0 = make_uint4(0, 0, 0, 0), A1 = A0;
    if (g < n8) {
        const uint4* p = (const uint4*)(bb + ((size_t)g << 3));
        A0 = p[0]; A1 = p[1];
    }
    while (g < n8) {
        const int gn = g + 512;
        uint4 B0 = make_uint4(0, 0, 0, 0), B1 = B0;
        if (gn < n8) {
            const uint4* p = (const uint4*)(bb + ((size_t)gn << 3));
            B0 = p[0]; B1 = p[1];
        }
        u32 e[8] = {A0.x, A0.y, A0.z, A0.w, A1.x, A1.y, A1.z, A1.w};
        u32 q[8];
#pragma unroll
        for (int j = 0; j < 8; ++j) q[j] = qx[e[j] & 0xFFFFFu];
#pragma unroll
        for (int j = 0; j < 8; ++j) {
            float a, b, c;
            dec_x(q[j], a, b, c);
            u32 r = (e[j] >> 20) & 3u; const float* wr = &w[r * 6];
            atomicAdd(&acc[(e[j] >> 22) * NR + r],
                pack_msg(a * wr[0] + b * wr[2] + c * wr[4],
                         a * wr[1] + b * wr[3] + c * wr[5]));
        }
        A0 = B0; A1 = B1; g = gn;
    }
    for (int i = (n8 << 3) + tid; i < n; i += 512) {
        u32 e0 = bb[i];
        u32 g0 = qx[e0 & 0xFFFFFu];
        float a, b, c;
        dec_x(g0, a, b, c);
        u32 r = (e0 >> 20) & 3u; const float* wr = &w[r * 6];
        atomicAdd(&acc[(e0 >> 22) * NR + r],
            pack_msg(a * wr[0] + b * wr[2] + c * wr[4],
                     a * wr[1] + b * wr[3] + c * wr[5]));
    }
    __syncthreads();

    // fused node1: root + bias + per-relation mean, relu; exact fp32 x here
    for (int l = tid; l < 1024; l += 512) {
        int node = (bk << BSH) + l;
        if (node >= NN) continue;
        float x0 = x[3 * node + 0], x1 = x[3 * node + 1], x2 = x[3 * node + 2];
        float o0 = x0 * root1[0] + x1 * root1[2] + x2 * root1[4] + b1[0];
        float o1 = x0 * root1[1] + x1 * root1[3] + x2 * root1[5] + b1[1];
#pragma unroll
        for (int r = 0; r < NR; ++r) {
            u64 wv = acc[l * NR + r];
            int c = (int)(wv >> 56);
            int s0i = (int)(wv & M28) - (c << 19);
            int s1i = (int)((wv >> 28) & M28) - (c << 19);
            float inv = (1.0f / 4096.0f) / (float)(c > 1 ? c : 1);
            o0 += (float)s0i * inv;
            o1 += (float)s1i * inv;
        }
        qh[node] = enc_h(fmaxf(o0, 0.0f), fmaxf(o1, 0.0f));
    }
}

__global__ __launch_bounds__(512, 8) void agg2_kernel(
    const u32* __restrict__ buf, const u32* __restrict__ cursor,
    const u32* __restrict__ qh, const float* __restrict__ W2,
    const float* __restrict__ root2, const float* __restrict__ b2,
    float* __restrict__ out)
{
    __shared__ u64 acc[1024 * NR];
    __shared__ float w[NR * 2 * 2];
    const int tid = threadIdx.x;
    for (int i = tid; i < 1024 * NR; i += 512) acc[i] = 0;
    if (tid < NR * 2 * 2) w[tid] = W2[tid];
    __syncthreads();

    const int bk = blockIdx.x;
    const int n = min((int)cursor[bk * CSTR], BCAP);
    const u32* bb = buf + (size_t)bk * BCAP;
    const int n8 = n >> 3;

    int g = tid;
    uint4 A0 = make_uint4(0, 0, 0, 0), A1 = A0;
    if (g < n8) {
        const uint4* p = (const uint4*)(bb + ((size_t)g << 3));
        A0 = p[0]; A1 = p[1];
    }
    while (g < n8) {
        const int gn = g + 512;
        uint4 B0 = make_uint4(0, 0, 0, 0), B1 = B0;
        if (gn < n8) {
            const uint4* p = (const uint4*)(bb + ((size_t)gn << 3));
            B0 = p[0]; B1 = p[1];
        }
        u32 e[8] = {A0.x, A0.y, A0.z, A0.w, A1.x, A1.y, A1.z, A1.w};
        u32 q[8];
#pragma unroll
        for (int j = 0; j < 8; ++j) q[j] = qh[e[j] & 0xFFFFFu];
#pragma unroll
        for (int j = 0; j < 8; ++j) {
            float a, b;
            dec_h(q[j], a, b);
            u32 r = (e[j] >> 20) & 3u; const float* wr = &w[r * 4];
            atomicAdd(&acc[(e[j] >> 22) * NR + r],
                pack_msg(a * wr[0] + b * wr[2], a * wr[1] + b * wr[3]));
        }
        A0 = B0; A1 = B1; g = gn;
    }
    for (int i = (n8 << 3) + tid; i < n; i += 512) {
        u32 e0 = bb[i];
        u32 g0 = qh[e0 & 0xFFFFFu];
        float a, b;
        dec_h(g0, a, b);
        u32 r = (e0 >> 20) & 3u; const float* wr = &w[r * 4];
        atomicAdd(&acc[(e0 >> 22) * NR + r],
            pack_msg(a * wr[0] + b * wr[2], a * wr[1] + b * wr[3]));
    }
    __syncthreads();

    for (int l = tid; l < 1024; l += 512) {
        int node = (bk << BSH) + l;
        if (node >= NN) continue;
        float hv0, hv1;
        dec_h(qh[node], hv0, hv1);
        float o0 = hv0 * root2[0] + hv1 * root2[2] + b2[0];
        float o1 = hv0 * root2[1] + hv1 * root2[3] + b2[1];
#pragma unroll
        for (int r = 0; r < NR; ++r) {
            u64 wv = acc[l * NR + r];
            int c = (int)(wv >> 56);
            int s0i = (int)(wv & M28) - (c << 19);
            int s1i = (int)((wv >> 28) & M28) - (c << 19);
            float inv = (1.0f / 4096.0f) / (float)(c > 1 ? c : 1);
            o0 += (float)s0i * inv;
            o1 += (float)s1i * inv;
        }
        float2 ov; ov.x = o0; ov.y = o1;
        ((float2*)out)[node] = ov;
    }
}

// ---------------- fallback path (proven R4, 56 MB ws) ----------------

__global__ __launch_bounds__(256) void edge1_kernel(
    const int* __restrict__ src, const int* __restrict__ dst, const int* __restrict__ rel,
    const float* __restrict__ x, const float* __restrict__ W1,
    u64* __restrict__ sums1)
{
    __shared__ float w[NR * 3 * 2];
    if (threadIdx.x < NR * 3 * 2) w[threadIdx.x] = W1[threadIdx.x];
    __syncthreads();
    int e = blockIdx.x * 256 + threadIdx.x;
    if (e >= NE) return;
    int s = src[e], d = dst[e], r = rel[e];
    float x0 = x[3 * s + 0], x1 = x[3 * s + 1], x2 = x[3 * s + 2];
    const float* wr = &w[r * 6];
    float m0 = x0 * wr[0] + x1 * wr[2] + x2 * wr[4];
    float m1 = x0 * wr[1] + x1 * wr[3] + x2 * wr[5];
    atomicAdd(&sums1[d * NR + r], pack_msg(m0, m1));
}

__global__ __launch_bounds__(256) void node1_kernel(
    const float* __restrict__ x, const u64* __restrict__ sums1,
    const float* __restrict__ root1, const float* __restrict__ b1,
    float* __restrict__ h)
{
    int n = blockIdx.x * 256 + threadIdx.x;
    if (n >= NN) return;
    float x0 = x[3 * n + 0], x1 = x[3 * n + 1], x2 = x[3 * n + 2];
    float o0 = x0 * root1[0] + x1 * root1[2] + x2 * root1[4] + b1[0];
    float o1 = x0 * root1[1] + x1 * root1[3] + x2 * root1[5] + b1[1];
#pragma unroll
    for (int r = 0; r < NR; ++r) {
        u64 wv = sums1[n * NR + r];
        int c = (int)(wv >> 56);
        int s0i = (int)(wv & M28) - (c << 19);
        int s1i = (int)((wv >> 28) & M28) - (c << 19);
        float inv = (1.0f / 4096.0f) / (float)(c > 1 ? c : 1);
        o0 += (float)s0i * inv;
        o1 += (float)s1i * inv;
    }
    float2 hv;
    hv.x = fmaxf(o0, 0.0f);
    hv.y = fmaxf(o1, 0.0f);
    ((float2*)h)[n] = hv;
}

__global__ __launch_bounds__(256) void edge2_kernel(
    const int* __restrict__ src, const int* __restrict__ dst, const int* __restrict__ rel,
    const float* __restrict__ h, const float* __restrict__ W2,
    u64* __restrict__ sums2)
{
    __shared__ float w[NR * 2 * 2];
    if (threadIdx.x < NR * 2 * 2) w[threadIdx.x] = W2[threadIdx.x];
    __syncthreads();
    int e = blockIdx.x * 256 + threadIdx.x;
    if (e >= NE) return;
    int s = src[e];
    float2 hs = ((const float2*)h)[s];
    if (hs.x == 0.0f && hs.y == 0.0f) return;
    int d = dst[e], r = rel[e];
    const float* wr = &w[r * 4];
    float m0 = hs.x * wr[0] + hs.y * wr[2];
    float m1 = hs.x * wr[1] + hs.y * wr[3];
    atomicAdd(&sums2[d * NR + r], pack_msg(m0, m1));
}

__global__ __launch_bounds__(256) void node2_kernel(
    const float* __restrict__ h, const u64* __restrict__ sums1, const u64* __restrict__ sums2,
    const float* __restrict__ root2, const float* __restrict__ b2,
    float* __restrict__ out)
{
    int n = blockIdx.x * 256 + threadIdx.x;
    if (n >= NN) return;
    float2 hv = ((const float2*)h)[n];
    float o0 = hv.x * root2[0] + hv.y * root2[2] + b2[0];
    float o1 = hv.x * root2[1] + hv.y * root2[3] + b2[1];
#pragma unroll
    for (int r = 0; r < NR; ++r) {
        u64 w1 = sums1[n * NR + r];
        u64 w2 = sums2[n * NR + r];
        int c    = (int)(w1 >> 56);
        int adds = (int)(w2 >> 56);
        int s0i = (int)(w2 & M28) - (adds << 19);
        int s1i = (int)((w2 >> 28) & M28) - (adds << 19);
        float inv = (1.0f / 4096.0f) / (float)(c > 1 ? c : 1);
        o0 += (float)s0i * inv;
        o1 += (float)s1i * inv;
    }
    float2 ov; ov.x = o0; ov.y = o1;
    ((float2*)out)[n] = ov;
}

extern "C" void kernel_launch(void* const* d_in, const int* in_sizes, int n_in,
                              void* d_out, int out_size, void* d_ws, size_t ws_size,
                              hipStream_t stream) {
    const float* x     = (const float*)d_in[0];
    const int*   ei    = (const int*)d_in[1];   // [2, NE]: row 0 = src, row 1 = dst
    const int*   rel   = (const int*)d_in[2];
    const float* W1    = (const float*)d_in[3];
    const float* root1 = (const float*)d_in[4];
    const float* b1    = (const float*)d_in[5];
    const float* W2    = (const float*)d_in[6];
    const float* root2 = (const float*)d_in[7];
    const float* b2    = (const float*)d_in[8];
    float* out = (float*)d_out;

    const int* src = ei;
    const int* dst = ei + NE;

    char* ws = (char*)d_ws;
    const int nb = (NN + 255) / 256;

    // Fast-path ws layout (BCAP=18368 -> same total need as R8 despite padded cursor):
    //   buf    @ 0          : NB*BCAP u32   = 71,782,144 B
    //   qx     @ 71,782,144 : NN u32        =  4,000,000 B
    //   qh     @ 75,782,144 : NN u32        =  4,000,000 B
    //   cursor @ 79,782,144 : NB*CSTR u32   =     62,528 B (line-padded)
    const size_t OFF_QX  = 71782144;
    const size_t OFF_QH  = 75782144;
    const size_t OFF_CUR = 79782144;
    const size_t WS_NEED = OFF_CUR + (size_t)NB * CSTR * sizeof(u32);

    if (ws_size >= WS_NEED) {
        u32* buf    = (u32*)ws;
        u32* qx     = (u32*)(ws + OFF_QX);
        u32* qh     = (u32*)(ws + OFF_QH);
        u32* cursor = (u32*)(ws + OFF_CUR);

        hipMemsetAsync(cursor, 0, (size_t)NB * CSTR * sizeof(u32), stream);
        prep_qx_kernel<<<nb, 256, 0, stream>>>(x, qx);
        scatter_kernel<<<NBLKB, 1024, 0, stream>>>(src, dst, rel, buf, cursor);
        agg1_kernel<<<NB, 512, 0, stream>>>(buf, cursor, qx, x, W1, root1, b1, qh);
        agg2_kernel<<<NB, 512, 0, stream>>>(buf, cursor, qh, W2, root2, b2, out);
    } else {
        // Fallback: R4 packed-atomic path (56 MB)
        u64*   sums1 = (u64*)ws;
        u64*   sums2 = (u64*)(ws + (size_t)24 * 1000 * 1000);
        float* h     = (float*)(ws + (size_t)48 * 1000 * 1000);
        const int eb = (NE + 255) / 256;

        hipMemsetAsync(sums1, 0, (size_t)NN * NR * sizeof(u64), stream);
        hipMemsetAsync(sums2, 0, (size_t)NN * NR * sizeof(u64), stream);
        edge1_kernel<<<eb, 256, 0, stream>>>(src, dst, rel, x, W1, sums1);
        node1_kernel<<<nb, 256, 0, stream>>>(x, sums1, root1, b1, h);
        edge2_kernel<<<eb, 256, 0, stream>>>(src, dst, rel, h, W2, sums2);
        node2_kernel<<<nb, 256, 0, stream>>>(h, sums1, sums2, root2, b2, out);
    }
}